// Round 12
// baseline (174.287 us; speedup 1.0000x reference)
//
#include <hip/hip_runtime.h>
#include <hip/hip_bf16.h>
#include <stdint.h>

// ---------------------------------------------------------------------------
// pcnn round 22: M-SPLIT — 2 waves/block (one per output-channel half),
// hidden state exchanged via LDS, targeting 3 waves/EU occupancy.
//  - 9 rounds of evidence: single-wave structure floor ~86us; idle = MFMA
//    latency uncoverable at 2 waves/EU; 2/EU forced by ~250-reg footprint.
//  - Split: wave w computes rows [16w,16w+16). Per-wave: X 100 + A 36 +
//    acc 8 ~ 160 regs -> amdgpu_waves_per_eu(3) fits without spill.
//  - Hidden state YL[25px][16col][32k] in LDS (25.6KB): each wave writes its
//    half (ds_write_b64: k-slots quad*8+wid*4, kperm identity preserved),
//    barrier, both read full frags (ds_read_b128), barrier.
//  - X rebuilt from LDS each layer -> layer loop ROLLS (nothing crosses the
//    back edge): code ~33KB -> ~16KB. Immediate pack (lowest reg pressure;
//    cross-wave TLP at 3/EU is the latency-hiding bet).
//  - Colors GEMM split by halves (wave0 c0-chain, wave1 c1-chain); logits
//    split by pixels (w0: p<13, w1: p>=13). Mix/staging strided by 128.
//  - LDS pool 26752B -> 6 blocks/CU x 2 waves = 12 waves = 3/EU.
//  - Tripwires: VGPR <=~170, WRITE ~16.3MB (spill alarm), absmax 0.015625.
// ---------------------------------------------------------------------------

typedef short bf16x8 __attribute__((ext_vector_type(8)));
typedef float f32x4  __attribute__((ext_vector_type(4)));

// d_ws: WALL bf16 [8 layers][9 taps][32 o(permuted rows)][32 c] @0 (73728 u16)
//   l=0: conv0 (c<8), l=1..6: mid, l=7 rows<6: logits; l=7 rows>=6: wpost frags
// f32 @ byte 147456: BALL[8][32](permuted) @0, BP32[32] @256 (zero-padded bpost)
#define WSB_N     73728
#define WSB_EMB   6144
#define WSF_BYTE  147456
#define WSF_BALL  0
#define WSF_BP32  256

// LDS layout (bytes):
//   YL @0: [25px][16col][32k] shorts = 25600 (hidden-state exchange)
//     aliased pre-layer0: stage @0 (25*136*2=6800), inpk @6800 (6144)
//     aliased phase-2:    smb @0 (25*98*4=9800)
//   colb @25600: [16b][18oc] f32 = 1152
#define L_STAGE_STRIDE 136
#define L_INPK   6800
#define L_COLB   25600
#define L_POOL   26752
#define SMB_STRIDE 98

__device__ __forceinline__ float b2f(unsigned short u) {
  union { unsigned int u; float f; } v; v.u = ((unsigned int)u) << 16; return v.f;
}
__device__ __forceinline__ unsigned short f2b(float f) {
  union { float f; unsigned int u; } v; v.f = f;
  unsigned int r = v.u + 0x7fffu + ((v.u >> 16) & 1u);  // RNE
  return (unsigned short)(r >> 16);
}
__device__ __forceinline__ unsigned int pk2(float lo, float hi) {
  __hip_bfloat162 h = __float22bfloat162_rn(make_float2(lo, hi));
  union { __hip_bfloat162 h; unsigned int u; } v; v.h = h; return v.u;
}
__device__ __forceinline__ bool sniff_is_f32(const void* w0raw) {
  const unsigned short* q = (const unsigned short*)w0raw;
  int hits = 0;
  #pragma unroll
  for (int i = 0; i < 64; ++i) {
    unsigned int e = (q[i] >> 7) & 0xFFu;
    if (e >= 130u) ++hits;
  }
  return hits > 0;
}
__device__ __forceinline__ float ldw(const void* p, long idx, bool f32) {
  return f32 ? ((const float*)p)[idx] : b2f(((const unsigned short*)p)[idx]);
}
// C-row m -> B-k-slot permutation (identity on k-slots: slot s <- channel s)
__device__ __forceinline__ int kperm(int m) {
  return (m < 16) ? ((m >> 2) * 8 + (m & 3))
                  : (((m - 16) >> 2) * 8 + 4 + (m & 3));
}

// ---------------- weight pre-pack (identical to R12..R18, verified) --------
__global__ void prep_weights(const void* __restrict__ w0,
                             const void* __restrict__ b0,
                             const void* __restrict__ wm,
                             const void* __restrict__ bm,
                             const void* __restrict__ wl,
                             const void* __restrict__ bl,
                             const void* __restrict__ wp,
                             const void* __restrict__ bp,
                             unsigned short* __restrict__ wsb,
                             float* __restrict__ wsf) {
  const bool f32 = sniff_is_f32(w0);
  int e = blockIdx.x * blockDim.x + threadIdx.x;
  if (e < WSB_N) {                        // WALL[l][t][o32][c32]
    int l = e / 9216, r = e % 9216, t = r / 1024, r2 = r % 1024;
    int o = r2 >> 5, c = r2 & 31;
    if (l == 7 && o >= 6) return;         // reserved for wpost frags
    float v = 0.f;
    if (l < 7) {
      int co = kperm(o);                  // original out-channel at row o
      if (co < 25) {
        if (l == 0) { if (c < 8)  v = ldw(w0, (co * 8 + c) * 9 + t, f32); }
        else        { if (c < 25) v = ldw(wm, (((l - 1) * 25 + co) * 25 + c) * 9 + t, f32); }
      }
    } else {
      if (c < 25) v = ldw(wl, (o * 25 + c) * 9 + t, f32);
    }
    wsb[e] = f2b(v);
  } else if (e < WSB_N + WSB_EMB) {
    // wpost frag pack: conceptual [hl2][chunk3][o32][k32], physical at
    // layer-7 rows >= 6: rowidx = hl*96+chunk*32+o -> (tap, row 6+rowidx%26)
    int idx = e - WSB_N;
    int hl = idx / 3072, rem = idx % 3072;
    int chunk = rem / 1024, r2 = rem % 1024;
    int o = r2 >> 5, k = r2 & 31;
    float w = (o < 18 && k < 25) ? ldw(wp, (o * 3 + chunk) * 25 + k, f32) : 0.f;
    unsigned short hi = f2b(w);
    unsigned short val = hl ? f2b(w - b2f(hi)) : hi;
    int rowidx = hl * 96 + chunk * 32 + o;
    int t = rowidx / 26, rr = 6 + rowidx % 26;
    wsb[7 * 9216 + t * 1024 + rr * 32 + k] = val;
  } else {
    int q = e - WSB_N - WSB_EMB;
    if (q < 256) {                        // BALL[l][32] (rows permuted, l<7)
      int l = q >> 5, m = q & 31;
      float v = 0.f;
      if (l < 7) {
        int co = kperm(m);
        if (co < 25) v = (l == 0) ? ldw(b0, co, f32) : ldw(bm, (l - 1) * 25 + co, f32);
      } else {
        if (m < 6) v = ldw(bl, m, f32);
      }
      wsf[WSF_BALL + q] = v;
    } else if (q < 288) {                 // BP32: zero-padded bpost
      int oc = q - 256;
      wsf[WSF_BP32 + oc] = (oc < 18) ? ldw(bp, oc, f32) : 0.f;
    }
  }
}

// ---------------- main kernel: 2 waves per 16 patches (M-split) ------------
__global__ __launch_bounds__(128)
__attribute__((amdgpu_waves_per_eu(3)))
void pcnn_mfma(
    const void* __restrict__ inp,
    const void* __restrict__ w0raw,
    const unsigned short* __restrict__ wsb,
    const float* __restrict__ wsf,
    void* __restrict__ out) {
  __shared__ __align__(16) unsigned char pool[L_POOL];
  short* stage = (short*)pool;              // [25px][136]   (pre-layer0)
  short* inpk  = (short*)(pool + L_INPK);   // [hl2][ic3][b16][k32] (pre-l0)
  short* YL    = (short*)pool;              // [25px][16col][32k] exchange
  float* colb  = (float*)(pool + L_COLB);   // [b16][18oc]
  float* smb   = (float*)pool;              // [25px][98]    (phase 2)

  const bool f32m = sniff_is_f32(w0raw);
  const int tid  = threadIdx.x;         // 0..127
  const int lane = tid & 63;
  const int wid  = tid >> 6;            // 0/1 = output-channel half
  const int col  = lane & 15;           // MFMA n (patch)
  const int quad = lane >> 4;
  const long g   = blockIdx.x;          // group of 16 patches

  // ---- colors A-frags (this wave's half) + bias ----
  bf16x8 WC[2][3];
  #pragma unroll
  for (int hl = 0; hl < 2; ++hl)
    #pragma unroll
    for (int ch = 0; ch < 3; ++ch) {
      const int rowidx = hl * 96 + ch * 32 + wid * 16 + col;
      const int t = rowidx / 26, rr = 6 + rowidx % 26;
      WC[hl][ch] = *(const bf16x8*)(wsb + 7 * 9216 + t * 1024 + rr * 32 + quad * 8);
    }
  f32x4 cacc = *(const f32x4*)(wsf + WSF_BP32 + wid * 16 + quad * 4);

  // ---- zero inpk pad slots k=25..31 (garbage NaN x 0-weight = NaN!) ----
  for (int i = tid; i < 672; i += 128) {
    int s = 25 + i % 7, rest = i / 7;     // rest = (hl*3+ic)*16+b
    inpk[rest * 32 + s] = 0;
  }

  // ---- stage input: 3200 elems / 128 threads = 25 each (batched loads) ----
  {
    float v[25];
    #pragma unroll
    for (int j = 0; j < 25; ++j)
      v[j] = ldw(inp, g * 3200 + j * 128 + tid, f32m);
    #pragma unroll
    for (int j = 0; j < 25; ++j) {
      const int e = j * 128 + tid;
      int b = e / 200, r = e % 200, c = r / 25, px = r % 25;
      unsigned short hi = f2b(v[j]);
      stage[px * L_STAGE_STRIDE + b * 8 + c] = hi;
      if (c < 3) {
        inpk[((0 * 3 + c) * 16 + b) * 32 + px] = hi;
        inpk[((1 * 3 + c) * 16 + b) * 32 + px] = f2b(v[j] - b2f(hi));
      }
    }
  }
  __syncthreads();

  // ---- colors GEMM: wave w runs its half's chain (9 MFMAs each) ----
  #pragma unroll
  for (int ch = 0; ch < 3; ++ch) {
    bf16x8 Bhi = *(const bf16x8*)(inpk + ((0 * 3 + ch) * 16 + col) * 32 + quad * 8);
    bf16x8 Blo = *(const bf16x8*)(inpk + ((1 * 3 + ch) * 16 + col) * 32 + quad * 8);
    cacc = __builtin_amdgcn_mfma_f32_16x16x32_bf16(WC[0][ch], Bhi, cacc, 0, 0, 0);
    cacc = __builtin_amdgcn_mfma_f32_16x16x32_bf16(WC[0][ch], Blo, cacc, 0, 0, 0);
    cacc = __builtin_amdgcn_mfma_f32_16x16x32_bf16(WC[1][ch], Bhi, cacc, 0, 0, 0);
  }
  if (wid == 0) {
    #pragma unroll
    for (int r = 0; r < 4; ++r) colb[col * 18 + quad * 4 + r] = cacc[r];
  } else if (quad == 0) {
    colb[col * 18 + 16] = cacc[0];
    colb[col * 18 + 17] = cacc[1];
  }

  // ---- layer-0 X: quad0 holds ch0..7 from stage, other quads zero ----
  bf16x8 X[25];
  #pragma unroll
  for (int p = 0; p < 25; ++p) {
    union { bf16x8 v; uint4 q4; } t;
    t.q4 = make_uint4(0u, 0u, 0u, 0u);
    if (quad == 0) t.q4 = *(const uint4*)(stage + p * L_STAGE_STRIDE + col * 8);
    X[p] = t.v;
  }
  __syncthreads();                        // stage/inpk reads done; YL writable

  // ---- 7 conv layers, ROLLED loop (X rebuilt from LDS each iter) ----
  #pragma unroll 1
  for (int l = 0; l < 7; ++l) {
    const unsigned short* WA = wsb + l * 9216;
    bf16x8 A[9];
    #pragma unroll
    for (int t = 0; t < 9; ++t)
      A[t] = *(const bf16x8*)(WA + t * 1024 + (wid * 16 + col) * 32 + quad * 8);
    const f32x4 bias = *(const f32x4*)(wsf + WSF_BALL + l * 32 + wid * 16 + quad * 4);
    #pragma unroll
    for (int p = 0; p < 25; ++p) {
      const int py = p / 5, pxx = p % 5;
      f32x4 ae = bias, ao = {0.f, 0.f, 0.f, 0.f};
      #pragma unroll
      for (int dy = -1; dy <= 1; ++dy)
        #pragma unroll
        for (int dx = -1; dx <= 1; ++dx)
          if ((unsigned)(py + dy) < 5u && (unsigned)(pxx + dx) < 5u) {
            const int t = (dy + 1) * 3 + (dx + 1);
            const int q = p + dy * 5 + dx;
            if (t & 1)
              ao = __builtin_amdgcn_mfma_f32_16x16x32_bf16(A[t], X[q], ao, 0, 0, 0);
            else
              ae = __builtin_amdgcn_mfma_f32_16x16x32_bf16(A[t], X[q], ae, 0, 0, 0);
          }
      // immediate pack + write own half: k-slots quad*8 + wid*4 + {0..3}
      union { uint2 u2; unsigned int uu[2]; } w2;
      w2.uu[0] = pk2(fmaxf(ae[0] + ao[0], 0.f), fmaxf(ae[1] + ao[1], 0.f));
      w2.uu[1] = pk2(fmaxf(ae[2] + ao[2], 0.f), fmaxf(ae[3] + ao[3], 0.f));
      *(uint2*)(YL + p * 512 + col * 32 + quad * 8 + wid * 4) = w2.u2;
    }
    __syncthreads();                      // both halves of YL written
    #pragma unroll
    for (int p = 0; p < 25; ++p)          // rebuild X (next layer / logits)
      X[p] = *(const bf16x8*)(YL + p * 512 + col * 32 + quad * 8);
    __syncthreads();                      // reads done; YL/smb writable
  }

  // ---- logits (rows<6, natural) split by pixels + softmax tail -> smb ----
  {
    const unsigned short* WA = wsb + 7 * 9216;
    bf16x8 A[9];
    #pragma unroll
    for (int t = 0; t < 9; ++t)
      A[t] = *(const bf16x8*)(WA + t * 1024 + col * 32 + quad * 8);
    const f32x4 biasl = *(const f32x4*)(wsf + WSF_BALL + 7 * 32 + quad * 4);
    #pragma unroll
    for (int p = 0; p < 25; ++p) {
      if ((p < 13) != (wid == 0)) continue;   // wave0: p<13, wave1: p>=13
      const int py = p / 5, pxx = p % 5;
      f32x4 ae = biasl, ao = {0.f, 0.f, 0.f, 0.f};
      #pragma unroll
      for (int dy = -1; dy <= 1; ++dy)
        #pragma unroll
        for (int dx = -1; dx <= 1; ++dx)
          if ((unsigned)(py + dy) < 5u && (unsigned)(pxx + dx) < 5u) {
            const int t = (dy + 1) * 3 + (dx + 1);
            const int q = p + dy * 5 + dx;
            if (t & 1)
              ao = __builtin_amdgcn_mfma_f32_16x16x32_bf16(A[t], X[q], ao, 0, 0, 0);
            else
              ae = __builtin_amdgcn_mfma_f32_16x16x32_bf16(A[t], X[q], ae, 0, 0, 0);
          }
      f32x4 a;
      a[0] = ae[0] + ao[0]; a[1] = ae[1] + ao[1];
      a[2] = ae[2] + ao[2]; a[3] = ae[3] + ao[3];
      float l4 = __shfl_xor(a[0], 16);
      float l5 = __shfl_xor(a[1], 16);
      if (quad == 0) {
        float m = fmaxf(fmaxf(fmaxf(a[0], a[1]), fmaxf(a[2], a[3])), fmaxf(l4, l5));
        float e0 = __expf(a[0] - m), e1 = __expf(a[1] - m), e2 = __expf(a[2] - m);
        float e3 = __expf(a[3] - m), e4 = __expf(l4 - m), e5 = __expf(l5 - m);
        float inv = 1.f / (e0 + e1 + e2 + e3 + e4 + e5);
        float* sp = smb + p * SMB_STRIDE + col * 6;
        sp[0] = e0 * inv; sp[1] = e1 * inv; sp[2] = e2 * inv;
        sp[3] = e3 * inv; sp[4] = e4 * inv; sp[5] = e5 * inv;
      }
    }
  }
  __syncthreads();

  // ---- mix + store: out[b][c][p] = sum_w colors[b][c*6+w] * sm[p][b][w] ----
  for (int e = tid; e < 1200; e += 128) {
    int b = e / 75, r = e % 75, c = r / 25, p = r % 25;
    float v = 0.f;
    #pragma unroll
    for (int w = 0; w < 6; ++w)
      v = fmaf(colb[b * 18 + c * 6 + w], smb[p * SMB_STRIDE + b * 6 + w], v);
    const long oidx = g * 1200 + e;
    if (f32m) ((float*)out)[oidx] = v;
    else      ((unsigned short*)out)[oidx] = f2b(v);
  }
}

extern "C" void kernel_launch(void* const* d_in, const int* in_sizes, int n_in,
                              void* d_out, int out_size, void* d_ws, size_t ws_size,
                              hipStream_t stream) {
  unsigned short* wsb = (unsigned short*)d_ws;
  float* wsf = (float*)((char*)d_ws + WSF_BYTE);
  const int B = in_sizes[0] / 200;  // 32768

  const int prep_n = WSB_N + WSB_EMB + 288;  // 80160
  prep_weights<<<(prep_n + 255) / 256, 256, 0, stream>>>(
      d_in[1], d_in[2], d_in[3], d_in[4], d_in[5], d_in[6], d_in[7], d_in[8],
      wsb, wsf);
  pcnn_mfma<<<B / 16, 128, 0, stream>>>(d_in[0], d_in[1], wsb, wsf, d_out);
}